// Round 4
// baseline (311.107 us; speedup 1.0000x reference)
//
#include <hip/hip_runtime.h>

// ---------------------------------------------------------------------------
// Compile-time Cayley table for Cl(4,0), blades in short-lex order.
// For each (i,k): exactly one output blade j = idx(ba ^ bb), sign from
// merge-swap parity (metric all +1). constexpr => folded after unrolling.
// ---------------------------------------------------------------------------
struct Tables {
    signed char  sgn[16][16];
    unsigned char out[16][16];
};

constexpr int pc4(int x) {
    return ((x >> 0) & 1) + ((x >> 1) & 1) + ((x >> 2) & 1) + ((x >> 3) & 1);
}

constexpr Tables make_tables() {
    Tables t{};
    int bitmaps[16] = {};
    int n = 0;
    for (int g = 0; g <= 4; ++g)
        for (int bm = 0; bm < 16; ++bm)
            if (pc4(bm) == g) bitmaps[n++] = bm;
    int inv[16] = {};
    for (int i = 0; i < 16; ++i) inv[bitmaps[i]] = i;
    for (int i = 0; i < 16; ++i) {
        for (int k = 0; k < 16; ++k) {
            const int ba = bitmaps[i];
            const int bb = bitmaps[k];
            int swaps = 0;
            for (int sh = ba >> 1; sh; sh >>= 1) swaps += pc4(sh & bb);
            t.sgn[i][k] = (swaps & 1) ? -1 : 1;
            t.out[i][k] = (unsigned char)inv[ba ^ bb];
        }
    }
    return t;
}

constexpr Tables TBL = make_tables();

// Row stride 17 floats: bank = (17*row + c) % 32; 17 odd => lanes 0..31 all
// distinct banks for fixed c, lane t+32 aliases lane t => 2-way (free, m136).
#define ROW 17

// Block = 256 threads = 256 multivectors per tile.
// Global traffic is 100% lane-contiguous float4; AoS gather happens in LDS.
__global__ __launch_bounds__(256) void clifford_gp_kernel(
        const float4* __restrict__ a4,
        const float4* __restrict__ b4,
        float4* __restrict__ o4,
        int n_mv) {
    __shared__ float lds_a[256 * ROW];
    __shared__ float lds_b[256 * ROW];

    const int t = threadIdx.x;
    const int base4 = blockIdx.x * 256 * 4;   // tile base in float4 units
    const int n4 = n_mv * 4;

    // ---- stage in: coalesced float4 loads, scalar scatter into padded rows
    #pragma unroll
    for (int r = 0; r < 4; ++r) {
        const int idx = r * 256 + t;
        if (base4 + idx < n4) {
            const float4 va = a4[base4 + idx];
            const float4 vb = b4[base4 + idx];
            const int mv = idx >> 2;
            const int q  = idx & 3;
            float* pa = &lds_a[mv * ROW + q * 4];
            pa[0] = va.x; pa[1] = va.y; pa[2] = va.z; pa[3] = va.w;
            float* pb = &lds_b[mv * ROW + q * 4];
            pb[0] = vb.x; pb[1] = vb.y; pb[2] = vb.z; pb[3] = vb.w;
        }
    }
    __syncthreads();

    // ---- compute: each thread owns row t (private) -> registers
    float av[16], bv[16], ov[16];
    #pragma unroll
    for (int c = 0; c < 16; ++c) av[c] = lds_a[t * ROW + c];
    #pragma unroll
    for (int c = 0; c < 16; ++c) bv[c] = lds_b[t * ROW + c];

    #pragma unroll
    for (int j = 0; j < 16; ++j) ov[j] = 0.0f;

    #pragma unroll
    for (int i = 0; i < 16; ++i) {
        #pragma unroll
        for (int k = 0; k < 16; ++k) {
            const int j = TBL.out[i][k];       // compile-time constant
            if (TBL.sgn[i][k] > 0) {
                ov[j] = fmaf(av[i], bv[k], ov[j]);
            } else {
                ov[j] = fmaf(-av[i], bv[k], ov[j]);
            }
        }
    }

    // ---- output: write own row (row-private vs compute reads, no barrier
    //      needed before this), then barrier, then coalesced gather-out.
    #pragma unroll
    for (int c = 0; c < 16; ++c) lds_a[t * ROW + c] = ov[c];
    __syncthreads();

    #pragma unroll
    for (int r = 0; r < 4; ++r) {
        const int idx = r * 256 + t;
        if (base4 + idx < n4) {
            const int mv = idx >> 2;
            const int q  = idx & 3;
            const float* po = &lds_a[mv * ROW + q * 4];
            o4[base4 + idx] = make_float4(po[0], po[1], po[2], po[3]);
        }
    }
}

extern "C" void kernel_launch(void* const* d_in, const int* in_sizes, int n_in,
                              void* d_out, int out_size, void* d_ws, size_t ws_size,
                              hipStream_t stream) {
    const float4* a4 = (const float4*)d_in[0];
    const float4* b4 = (const float4*)d_in[1];
    // d_in[2] (cayley) intentionally unused: table folded at compile time.
    float4* o4 = (float4*)d_out;

    const int n_mv = in_sizes[0] / 16;            // 2048*1024 = 2,097,152
    const int block = 256;
    const int grid = (n_mv + block - 1) / block;  // 8192 blocks

    clifford_gp_kernel<<<grid, block, 0, stream>>>(a4, b4, o4, n_mv);
}

// Round 5
// 309.977 us; speedup vs baseline: 1.0036x; 1.0036x over previous
//
#include <hip/hip_runtime.h>

// ---------------------------------------------------------------------------
// Compile-time Cayley table for Cl(4,0), blades in short-lex order.
// For each (i,k): exactly one output blade j = idx(ba ^ bb), sign from
// merge-swap parity (metric all +1). constexpr => folded after unrolling.
// ---------------------------------------------------------------------------
struct Tables {
    signed char  sgn[16][16];
    unsigned char out[16][16];
};

constexpr int pc4(int x) {
    return ((x >> 0) & 1) + ((x >> 1) & 1) + ((x >> 2) & 1) + ((x >> 3) & 1);
}

constexpr Tables make_tables() {
    Tables t{};
    int bitmaps[16] = {};
    int n = 0;
    for (int g = 0; g <= 4; ++g)
        for (int bm = 0; bm < 16; ++bm)
            if (pc4(bm) == g) bitmaps[n++] = bm;
    int inv[16] = {};
    for (int i = 0; i < 16; ++i) inv[bitmaps[i]] = i;
    for (int i = 0; i < 16; ++i) {
        for (int k = 0; k < 16; ++k) {
            const int ba = bitmaps[i];
            const int bb = bitmaps[k];
            int swaps = 0;
            for (int sh = ba >> 1; sh; sh >>= 1) swaps += pc4(sh & bb);
            t.sgn[i][k] = (swaps & 1) ? -1 : 1;
            t.out[i][k] = (unsigned char)inv[ba ^ bb];
        }
    }
    return t;
}

constexpr Tables TBL = make_tables();

// ROW = 20 floats (80 B): 16B-aligned rows => all LDS ops are b128;
// start bank 20*t mod 32 spreads over 8 banksets => <=4-way conflicts (1.58x),
// vs 32-way for ROW=16. LDS/block = 2*256*20*4 = 40960 B => exactly 4 blocks/CU.
#define ROW 20

__global__ __launch_bounds__(256) void clifford_gp_kernel(
        const float4* __restrict__ a4,
        const float4* __restrict__ b4,
        float4* __restrict__ o4,
        int n_mv) {
    __shared__ __align__(16) float lds_a[256 * ROW];
    __shared__ __align__(16) float lds_b[256 * ROW];

    const int t = threadIdx.x;
    const long long base4 = (long long)blockIdx.x * 1024;  // tile base (float4 units)
    const long long n4 = (long long)n_mv * 4;
    const bool full = (base4 + 1024) <= n4;   // uniform: whole tile in range

    // ---- phase 1: issue ALL 8 global loads before ANY LDS write (MLP = 8).
    float4 va[4], vb[4];
    if (full) {
        #pragma unroll
        for (int r = 0; r < 4; ++r) va[r] = a4[base4 + r * 256 + t];
        #pragma unroll
        for (int r = 0; r < 4; ++r) vb[r] = b4[base4 + r * 256 + t];
    } else {
        #pragma unroll
        for (int r = 0; r < 4; ++r) {
            const long long g = base4 + r * 256 + t;
            va[r] = (g < n4) ? a4[g] : make_float4(0.f, 0.f, 0.f, 0.f);
            vb[r] = (g < n4) ? b4[g] : make_float4(0.f, 0.f, 0.f, 0.f);
        }
    }

    // ---- phase 2: scatter into padded LDS rows (b128 stores, 16B-aligned)
    #pragma unroll
    for (int r = 0; r < 4; ++r) {
        const int idx = r * 256 + t;
        const int mv = idx >> 2;
        const int q  = idx & 3;
        *reinterpret_cast<float4*>(&lds_a[mv * ROW + q * 4]) = va[r];
        *reinterpret_cast<float4*>(&lds_b[mv * ROW + q * 4]) = vb[r];
    }
    __syncthreads();

    // ---- phase 3: own row -> registers (b128 reads), 256 signed FMAs
    float av[16], bv[16], ov[16];
    #pragma unroll
    for (int j = 0; j < 4; ++j) {
        const float4 ta = *reinterpret_cast<const float4*>(&lds_a[t * ROW + j * 4]);
        av[j * 4 + 0] = ta.x; av[j * 4 + 1] = ta.y;
        av[j * 4 + 2] = ta.z; av[j * 4 + 3] = ta.w;
        const float4 tb = *reinterpret_cast<const float4*>(&lds_b[t * ROW + j * 4]);
        bv[j * 4 + 0] = tb.x; bv[j * 4 + 1] = tb.y;
        bv[j * 4 + 2] = tb.z; bv[j * 4 + 3] = tb.w;
    }

    #pragma unroll
    for (int j = 0; j < 16; ++j) ov[j] = 0.0f;

    #pragma unroll
    for (int i = 0; i < 16; ++i) {
        #pragma unroll
        for (int k = 0; k < 16; ++k) {
            const int j = TBL.out[i][k];       // compile-time constant
            if (TBL.sgn[i][k] > 0) {
                ov[j] = fmaf(av[i], bv[k], ov[j]);
            } else {
                ov[j] = fmaf(-av[i], bv[k], ov[j]);
            }
        }
    }

    // ---- phase 4: result row back to LDS (row-private; barrier; gather-out)
    #pragma unroll
    for (int j = 0; j < 4; ++j) {
        *reinterpret_cast<float4*>(&lds_a[t * ROW + j * 4]) =
            make_float4(ov[j * 4 + 0], ov[j * 4 + 1], ov[j * 4 + 2], ov[j * 4 + 3]);
    }
    __syncthreads();

    if (full) {
        #pragma unroll
        for (int r = 0; r < 4; ++r) {
            const int idx = r * 256 + t;
            const int mv = idx >> 2;
            const int q  = idx & 3;
            o4[base4 + idx] =
                *reinterpret_cast<const float4*>(&lds_a[mv * ROW + q * 4]);
        }
    } else {
        #pragma unroll
        for (int r = 0; r < 4; ++r) {
            const int idx = r * 256 + t;
            if (base4 + idx < n4) {
                const int mv = idx >> 2;
                const int q  = idx & 3;
                o4[base4 + idx] =
                    *reinterpret_cast<const float4*>(&lds_a[mv * ROW + q * 4]);
            }
        }
    }
}

extern "C" void kernel_launch(void* const* d_in, const int* in_sizes, int n_in,
                              void* d_out, int out_size, void* d_ws, size_t ws_size,
                              hipStream_t stream) {
    const float4* a4 = (const float4*)d_in[0];
    const float4* b4 = (const float4*)d_in[1];
    // d_in[2] (cayley) intentionally unused: table folded at compile time.
    float4* o4 = (float4*)d_out;

    const int n_mv = in_sizes[0] / 16;            // 2048*1024 = 2,097,152
    const int block = 256;
    const int grid = (n_mv + block - 1) / block;  // 8192 blocks

    clifford_gp_kernel<<<grid, block, 0, stream>>>(a4, b4, o4, n_mv);
}